// Round 3
// baseline (1690.416 us; speedup 1.0000x reference)
//
#include <hip/hip_runtime.h>
#include <hip/hip_bf16.h>

typedef unsigned short u16;
typedef __attribute__((ext_vector_type(8))) short short8;
typedef __attribute__((ext_vector_type(4))) float f32x4;
typedef __attribute__((ext_vector_type(8))) unsigned short ushort8v;

#define NVOX 200000
#define NOFF 27
#define NBLK 1563

__device__ __forceinline__ u16 f2bf(float f) {
    __hip_bfloat16 h = __float2bfloat16(f);
    return *reinterpret_cast<u16*>(&h);
}
__device__ __forceinline__ float bf2f(u16 u) {
    union { unsigned int i; float f; } v;
    v.i = ((unsigned int)u) << 16;
    return v.f;
}

// ---------------------------------------------------------------------------
// prep: cast x -> bf16 (vec4), transpose-cast W1/W2 -> [off][co][ci] bf16
// ---------------------------------------------------------------------------
__global__ __launch_bounds__(256) void prep_kernel(
    const float* __restrict__ x, const float* __restrict__ W1,
    const float* __restrict__ W2, u16* __restrict__ xb,
    u16* __restrict__ w1t, u16* __restrict__ w2t)
{
    const int XV = NVOX * 96 / 4;     // 4,800,000 vec4 jobs
    const int WE = NOFF * 96 * 192;   // 497,664
    int t = blockIdx.x * 256 + threadIdx.x;
    if (t < XV) {
        float4 v = *(const float4*)(x + (size_t)t * 4);
        ushort4 o;
        o.x = f2bf(v.x); o.y = f2bf(v.y); o.z = f2bf(v.z); o.w = f2bf(v.w);
        *(ushort4*)(xb + (size_t)t * 4) = o;
    } else if (t < XV + WE) {
        int e = t - XV;
        int off = e / 18432, rem = e % 18432;
        int co = rem / 96, ci = rem % 96;   // w1t: [off][co:192][ci:96]
        w1t[e] = f2bf(W1[off * 18432 + ci * 192 + co]);
    } else if (t < XV + 2 * WE) {
        int e = t - XV - WE;
        int off = e / 18432, rem = e % 18432;
        int co = rem / 192, ci = rem % 192; // w2t: [off][co:96][ci:192]
        w2t[e] = f2bf(W2[off * 18432 + ci * 96 + co]);
    }
}

// ---------------------------------------------------------------------------
// conv: pipelined explicit-GEMM sparse conv, bf16 MFMA, f32 accum.
//   COUT: out channels; WN: waves along N (conv1: 4, conv2: 2); HFDIV: K
//   phases per offset (conv1: 1, conv2: 2); GOFF: offsets per lsrc group.
//   Block: 128 voxels x COUT, 512 threads = 8 waves (WM x WN grid).
//   2-deep A-gather prefetch, 1-deep W prefetch, 2 barriers/step.
//   Epilogue: per-block BN partial sums (fused statsA) from f32 acc.
// ---------------------------------------------------------------------------
template<int COUT, int WN, int HFDIV, int GOFF>
__global__ __launch_bounds__(512, 4) void conv_mfma(
    const u16* __restrict__ xb, const int* __restrict__ idxp,
    const int* __restrict__ mskp, const u16* __restrict__ Wt,
    u16* __restrict__ hout, float* __restrict__ part)
{
    constexpr int CIN  = 96 * HFDIV;      // input-channel stride of source
    constexpr int RCH  = 12;              // 16B chunks per 96-ch row
    constexpr int RP   = 104;             // padded LDS row (bf16 units)
    constexpr int WM   = 8 / WN;
    constexpr int FM   = 128 / (WM * 16);
    constexpr int FN   = COUT / (WN * 16);
    constexpr int SG   = GOFF * HFDIV;    // steps per group
    constexpr int NG   = NOFF / GOFF;     // groups
    constexpr int WCHN = COUT * RCH;      // W chunks per step
    constexpr int WCH  = (WCHN + 511) / 512;

    __shared__ u16 ldsA[128 * RP];
    __shared__ u16 ldsW[COUT * RP];
    __shared__ int lsrcL[GOFF * 128];

    const int tid  = threadIdx.x;
    const int row0 = blockIdx.x * 128;
    const int lane = tid & 63;
    const int wid  = tid >> 6;
    const int wm   = wid / WN;
    const int wn   = wid % WN;
    const int lr   = lane & 15;
    const int lk   = lane >> 4;

    f32x4 acc[FM][FN];
#pragma unroll
    for (int m = 0; m < FM; ++m)
#pragma unroll
        for (int n = 0; n < FN; ++n)
            acc[m][n] = (f32x4){0.f, 0.f, 0.f, 0.f};

    const int aoff0 = (wm * (FM * 16) + lr) * RP + lk * 8;
    const int boff0 = (wn * (FN * 16) + lr) * RP + lk * 8;

    // hoisted per-thread staging constants (avoid div-by-12 in the hot loop)
    int aRow[3], aDst[3], aSrc[3];
#pragma unroll
    for (int it = 0; it < 3; ++it) {
        int l = it * 512 + tid;
        int r = l / RCH, c = l % RCH;
        aRow[it] = r;
        aDst[it] = r * RP + c * 8;
        aSrc[it] = c * 8;
    }
    int wDst[WCH], wSrc[WCH];
    bool wOk[WCH];
#pragma unroll
    for (int it = 0; it < WCH; ++it) {
        int l = it * 512 + tid;
        wOk[it]  = (l < WCHN);
        int ll   = wOk[it] ? l : 0;
        int co = ll / RCH, c = ll % RCH;
        wDst[it] = co * RP + c * 8;
        wSrc[it] = co * CIN + c * 8;
    }

    uint4 sA[3], sB[3], wR[WCH];

    auto issueA = [&](int step, uint4 (&s)[3]) {
        int offg = step / HFDIV, hf = step % HFDIV;
#pragma unroll
        for (int it = 0; it < 3; ++it) {
            int sv = lsrcL[offg * 128 + aRow[it]];
            uint4 v = {0u, 0u, 0u, 0u};
            if (sv >= 0)
                v = *(const uint4*)(xb + (size_t)sv * CIN + hf * 96 + aSrc[it]);
            s[it] = v;
        }
    };
    auto issueW = [&](int step, int gbase) {
        int off = gbase + step / HFDIV, hf = step % HFDIV;
        const u16* wg = Wt + (size_t)off * (COUT * CIN) + hf * 96;
#pragma unroll
        for (int it = 0; it < WCH; ++it)
            if (wOk[it]) wR[it] = *(const uint4*)(wg + wSrc[it]);
    };
    auto body = [&](int cur, uint4 (&slot)[3], int gbase) {
        __syncthreads();                       // prev MFMA reads done
#pragma unroll
        for (int it = 0; it < 3; ++it)
            *(uint4*)(ldsA + aDst[it]) = slot[it];
#pragma unroll
        for (int it = 0; it < WCH; ++it)
            if (wOk[it]) *(uint4*)(ldsW + wDst[it]) = wR[it];
        if (cur + 1 < SG) issueW(cur + 1, gbase);   // W: 1-deep prefetch
        if (cur + 2 < SG) issueA(cur + 2, slot);    // A: 2-deep prefetch
        __syncthreads();                       // tiles ready
#pragma unroll
        for (int ks = 0; ks < 3; ++ks) {
            short8 af[FM], bf_[FN];
#pragma unroll
            for (int m = 0; m < FM; ++m)
                af[m] = *(const short8*)(ldsA + aoff0 + m * 16 * RP + ks * 32);
#pragma unroll
            for (int n = 0; n < FN; ++n)
                bf_[n] = *(const short8*)(ldsW + boff0 + n * 16 * RP + ks * 32);
#pragma unroll
            for (int n = 0; n < FN; ++n)
#pragma unroll
                for (int m = 0; m < FM; ++m)
                    acc[m][n] = __builtin_amdgcn_mfma_f32_16x16x32_bf16(
                        af[m], bf_[n], acc[m][n], 0, 0, 0);
        }
    };

#pragma unroll 1
    for (int g = 0; g < NG; ++g) {
        const int gbase = g * GOFF;
        __syncthreads();                       // prev group's lsrc reads done
#pragma unroll
        for (int it = 0; it < (GOFF * 128 + 511) / 512; ++it) {
            int l = it * 512 + tid;
            if (l < GOFF * 128) {
                int o = l >> 7;
                int r = row0 + (l & 127);
                int rr = r < NVOX ? r : NVOX - 1;
                int mv = mskp[(size_t)(gbase + o) * NVOX + rr];
                int iv = idxp[(size_t)(gbase + o) * NVOX + rr];
                lsrcL[l] = (r < NVOX && mv > 0) ? iv : -1;
            }
        }
        __syncthreads();
        issueW(0, gbase);
        issueA(0, sA);
        issueA(1, sB);
        int c = 0;
#pragma unroll 1
        for (; c + 1 < SG; c += 2) { body(c, sA, gbase); body(c + 1, sB, gbase); }
        if (SG & 1) body(SG - 1, sA, gbase);
    }

    // ---- fused BN statsA: per-block partial sum/sumsq per channel ----
    __syncthreads();                           // last MFMA reads of ldsA done
    float* smf = (float*)ldsA;                 // overlay [WM][COUT][2]
#pragma unroll
    for (int n = 0; n < FN; ++n) {
        float s1 = 0.f, s2 = 0.f;
#pragma unroll
        for (int m = 0; m < FM; ++m)
#pragma unroll
            for (int q = 0; q < 4; ++q) {
                float v = acc[m][n][q];
                s1 += v; s2 += v * v;
            }
        s1 += __shfl_xor(s1, 16); s1 += __shfl_xor(s1, 32);
        s2 += __shfl_xor(s2, 16); s2 += __shfl_xor(s2, 32);
        if (lane < 16) {
            int col = wn * (FN * 16) + n * 16 + lr;
            smf[(wm * COUT + col) * 2 + 0] = s1;
            smf[(wm * COUT + col) * 2 + 1] = s2;
        }
    }
    __syncthreads();
    if (tid < 2 * COUT) {
        int z = tid / COUT, cc = tid % COUT;
        float v = 0.f;
#pragma unroll
        for (int w = 0; w < WM; ++w) v += smf[(w * COUT + cc) * 2 + z];
        part[(size_t)blockIdx.x * (2 * COUT) + z * COUT + cc] = v;
    }

    // ---- store h (bf16): D layout col=lane&15, row=(lane>>4)*4+q ----
#pragma unroll
    for (int m = 0; m < FM; ++m) {
#pragma unroll
        for (int q = 0; q < 4; ++q) {
            int row = row0 + wm * (FM * 16) + m * 16 + lk * 4 + q;
            if (row < NVOX) {
#pragma unroll
                for (int n = 0; n < FN; ++n) {
                    int col = wn * (FN * 16) + n * 16 + lr;
                    hout[(size_t)row * COUT + col] = f2bf(acc[m][n][q]);
                }
            }
        }
    }
}

// ---------------------------------------------------------------------------
// BN stats reduce: sum partials over NBLK blocks, emit scale/shift
// ---------------------------------------------------------------------------
template<int COUT>
__global__ __launch_bounds__(256) void bn_statsB(
    const float* __restrict__ part, const float* __restrict__ g,
    const float* __restrict__ bv, float* __restrict__ ss)
{
    const int c = blockIdx.x;
    const int t = threadIdx.x;
    float s1 = 0.f, s2 = 0.f;
    for (int b = t; b < NBLK; b += 256) {
        s1 += part[(size_t)b * 2 * COUT + c];
        s2 += part[(size_t)b * 2 * COUT + COUT + c];
    }
#pragma unroll
    for (int d = 1; d < 64; d <<= 1) {
        s1 += __shfl_xor(s1, d);
        s2 += __shfl_xor(s2, d);
    }
    __shared__ float rs[8];
    int w = t >> 6;
    if ((t & 63) == 0) { rs[w] = s1; rs[4 + w] = s2; }
    __syncthreads();
    if (t == 0) {
        s1 = rs[0] + rs[1] + rs[2] + rs[3];
        s2 = rs[4] + rs[5] + rs[6] + rs[7];
        float mu  = s1 * (1.0f / NVOX);
        float var = s2 * (1.0f / NVOX) - mu * mu;
        float sc  = g[c] * rsqrtf(var + 1e-5f);
        ss[c] = sc;
        ss[COUT + c] = bv[c] - mu * sc;
    }
}

// ---------------------------------------------------------------------------
// apply BN + ReLU in place (bf16), vec8
// ---------------------------------------------------------------------------
template<int COUT>
__global__ __launch_bounds__(256) void bn_apply_relu(
    u16* __restrict__ h, const float* __restrict__ ss)
{
    int t = blockIdx.x * 256 + threadIdx.x;   // < NVOX*COUT/8
    int c0 = (t * 8) % COUT;
    ushort8v v = *(ushort8v*)(h + (size_t)t * 8);
#pragma unroll
    for (int j = 0; j < 8; ++j) {
        float f = bf2f(v[j]);
        f = fmaxf(f * ss[c0 + j] + ss[COUT + c0 + j], 0.f);
        v[j] = f2bf(f);
    }
    *(ushort8v*)(h + (size_t)t * 8) = v;
}

// ---------------------------------------------------------------------------
// final: out = relu(scale2*h2 + shift2 + x), f32 out, vec8
// ---------------------------------------------------------------------------
__global__ __launch_bounds__(256) void final_kernel(
    const u16* __restrict__ h2, const float* __restrict__ x,
    const float* __restrict__ ss, float* __restrict__ out)
{
    int t = blockIdx.x * 256 + threadIdx.x;   // < NVOX*96/8
    int c0 = (t * 8) % 96;
    ushort8v v = *(const ushort8v*)(h2 + (size_t)t * 8);
    float4 x0 = *(const float4*)(x + (size_t)t * 8);
    float4 x1 = *(const float4*)(x + (size_t)t * 8 + 4);
    float xs[8] = {x0.x, x0.y, x0.z, x0.w, x1.x, x1.y, x1.z, x1.w};
    float o[8];
#pragma unroll
    for (int j = 0; j < 8; ++j) {
        float f = bf2f(v[j]) * ss[c0 + j] + ss[96 + c0 + j] + xs[j];
        o[j] = fmaxf(f, 0.f);
    }
    *(float4*)(out + (size_t)t * 8)     = (float4){o[0], o[1], o[2], o[3]};
    *(float4*)(out + (size_t)t * 8 + 4) = (float4){o[4], o[5], o[6], o[7]};
}

// ---------------------------------------------------------------------------
extern "C" void kernel_launch(void* const* d_in, const int* in_sizes, int n_in,
                              void* d_out, int out_size, void* d_ws, size_t ws_size,
                              hipStream_t stream)
{
    const float* x    = (const float*)d_in[0];
    const int*   idx  = (const int*)d_in[1];
    const int*   mask = (const int*)d_in[2];
    const float* W1   = (const float*)d_in[3];
    const float* g1   = (const float*)d_in[4];
    const float* b1   = (const float*)d_in[5];
    const float* W2   = (const float*)d_in[6];
    const float* g2   = (const float*)d_in[7];
    const float* b2   = (const float*)d_in[8];

    unsigned char* ws = (unsigned char*)d_ws;
    u16*  xb   = (u16*)ws;                          // 38,400,000 B
    u16*  w1t  = (u16*)(ws + 38400000);             //    995,328 B
    u16*  w2t  = (u16*)(ws + 39395328);             //    995,328 B
    u16*  h2   = (u16*)(ws + 40390656);             // 38,400,000 B
    float* part = (float*)(ws + 78790656);          //  2,400,768 B (1563*384*4)
    float* ss1  = (float*)(ws + 81191424);          //      1,536 B
    float* ss2  = (float*)(ws + 81192960);          //        768 B

    u16* h = (u16*)d_out;         // reuse d_out (76.8MB) as [N][192] bf16

    prep_kernel<<<22638, 256, 0, stream>>>(x, W1, W2, xb, w1t, w2t);

    // conv1: COUT=192, WN=4 (2m x 4n), HFDIV=1, groups of 9 offsets
    conv_mfma<192, 4, 1, 9><<<NBLK, 512, 0, stream>>>(xb, idx, mask, w1t, h, part);
    bn_statsB<192><<<192, 256, 0, stream>>>(part, g1, b1, ss1);
    bn_apply_relu<192><<<18750, 256, 0, stream>>>(h, ss1);

    // conv2: COUT=96, WN=2 (4m x 2n), HFDIV=2 (K=192 in two 96 phases)
    conv_mfma<96, 2, 2, 9><<<NBLK, 512, 0, stream>>>(h, idx, mask, w2t, h2, part);
    bn_statsB<96><<<96, 256, 0, stream>>>(part, g2, b2, ss2);
    final_kernel<<<9375, 256, 0, stream>>>(h2, x, ss2, (float*)d_out);
}

// Round 4
// 644.008 us; speedup vs baseline: 2.6248x; 2.6248x over previous
//
#include <hip/hip_runtime.h>
#include <hip/hip_bf16.h>

typedef unsigned short u16;
typedef __attribute__((ext_vector_type(8))) short short8;
typedef __attribute__((ext_vector_type(4))) float f32x4;
typedef __attribute__((ext_vector_type(8))) unsigned short ushort8v;

#define NVOX 200000
#define NOFF 27
#define NBLK 1563

__device__ __forceinline__ u16 f2bf(float f) {
    __hip_bfloat16 h = __float2bfloat16(f);
    return *reinterpret_cast<u16*>(&h);
}
__device__ __forceinline__ float bf2f(u16 u) {
    union { unsigned int i; float f; } v;
    v.i = ((unsigned int)u) << 16;
    return v.f;
}

#define GLOAD_LDS16(g, l)                                                     \
    __builtin_amdgcn_global_load_lds(                                         \
        (const __attribute__((address_space(1))) unsigned int*)(g),           \
        (__attribute__((address_space(3))) unsigned int*)(l), 16, 0, 0)

// ---------------------------------------------------------------------------
// prep: cast x -> bf16; repack W1/W2 into fragment-major bf16:
//   w?t[(kidx*NCO + nco)*512 + lane*8 + j]  holds W[off][k][co] with
//   kidx = off*3*HFDIV + kstep, co = nco*16 + (lane&15),
//   k = kstep*32 + (lane>>4)*8 + j.  Also zero-fills zbuf (256 B).
// ---------------------------------------------------------------------------
__global__ __launch_bounds__(256) void prep_kernel(
    const float* __restrict__ x, const float* __restrict__ W1,
    const float* __restrict__ W2, u16* __restrict__ xb,
    u16* __restrict__ w1t, u16* __restrict__ w2t, float* __restrict__ zbuf)
{
    const int XV = NVOX * 96 / 4;     // 4,800,000 vec4 cast jobs
    const int WC = 62208;             // W chunk jobs per conv (27*36*64)
    int t = blockIdx.x * 256 + threadIdx.x;
    if (blockIdx.x == 0 && threadIdx.x < 64) zbuf[threadIdx.x] = 0.f;
    if (t < XV) {
        float4 v = *(const float4*)(x + (size_t)t * 4);
        ushort4 o;
        o.x = f2bf(v.x); o.y = f2bf(v.y); o.z = f2bf(v.z); o.w = f2bf(v.w);
        *(ushort4*)(xb + (size_t)t * 4) = o;
    } else if (t < XV + WC) {
        int j = t - XV;
        int lane = j & 63, rest = j >> 6;
        int nco = rest % 12, rest2 = rest / 12;
        int ks = rest2 % 3, off = rest2 / 3;
        int co = nco * 16 + (lane & 15);
        int kb = ks * 32 + (lane >> 4) * 8;
        const float* src = W1 + (size_t)off * 18432 + (size_t)kb * 192 + co;
        ushort8v ov;
#pragma unroll
        for (int jj = 0; jj < 8; ++jj) ov[jj] = f2bf(src[(size_t)jj * 192]);
        *(ushort8v*)(w1t + (size_t)j * 8) = ov;
    } else if (t < XV + 2 * WC) {
        int j = t - XV - WC;
        int lane = j & 63, rest = j >> 6;
        int nco = rest % 6, rest2 = rest / 6;
        int kk = rest2 % 6, off = rest2 / 6;
        int co = nco * 16 + (lane & 15);
        int kb = kk * 32 + (lane >> 4) * 8;
        const float* src = W2 + (size_t)off * 18432 + (size_t)kb * 96 + co;
        ushort8v ov;
#pragma unroll
        for (int jj = 0; jj < 8; ++jj) ov[jj] = f2bf(src[(size_t)jj * 96]);
        *(ushort8v*)(w2t + (size_t)j * 8) = ov;
    }
}

// ---------------------------------------------------------------------------
// conv: explicit-GEMM sparse conv, bf16 MFMA, f32 accum.
//   A: global_load_lds double-buffer, mod-12 rotated chunks (conflict fix),
//      masked rows read a zero page.  W: per-wave register frags from
//      fragment-major layout (L2-hot), 1-ks lookahead.  1 barrier/step.
//   Epilogue: fused BN partial sums + bf16 store.
// ---------------------------------------------------------------------------
template<int COUT, int WN, int HFDIV>
__global__ __launch_bounds__(512, 4) void conv_mfma(
    const u16* __restrict__ xb, const int* __restrict__ idxp,
    const int* __restrict__ mskp, const u16* __restrict__ Wt,
    const float* __restrict__ zbuf, u16* __restrict__ hout,
    float* __restrict__ part)
{
    constexpr int CIN  = 96 * HFDIV;
    constexpr int WM   = 8 / WN;
    constexpr int FM   = 128 / (WM * 16);
    constexpr int FN   = COUT / (WN * 16);
    constexpr int NCO  = COUT / 16;
    constexpr int SG   = NOFF * HFDIV;     // K-steps total
    constexpr int BUFU = 128 * 96;         // u16 per A buffer

    __shared__ u16 ldsA[2 * BUFU];         // 49152 B
    __shared__ int lsrcL[NOFF * 128];      // 13824 B

    const int tid  = threadIdx.x;
    const int row0 = blockIdx.x * 128;
    const int lane = tid & 63;
    const int wid  = tid >> 6;
    const int wm   = wid / WN;
    const int wn   = wid % WN;
    const int lr   = lane & 15;
    const int lk   = lane >> 4;

    // ---- stage lsrc table for all 27 offsets ----
#pragma unroll
    for (int it = 0; it < 7; ++it) {
        int l = it * 512 + tid;
        if (l < NOFF * 128) {
            int o = l >> 7, r = row0 + (l & 127);
            int rr = r < NVOX ? r : NVOX - 1;
            int mv = mskp[(size_t)o * NVOX + rr];
            int iv = idxp[(size_t)o * NVOX + rr];
            lsrcL[l] = (r < NVOX && mv > 0) ? iv : -1;
        }
    }

    // per-thread A-staging constants: 3 chunks, rotated source chunk
    int aRow[3], aGcOff[3];
#pragma unroll
    for (int it = 0; it < 3; ++it) {
        int l = it * 512 + tid;
        int r = l / 12, c = l % 12;
        aRow[it] = r;
        aGcOff[it] = ((c + r) % 12) * 8;   // u16 offset within source row
    }
    // per-m A-read constants
    int aBase[FM], d0m[FM];
#pragma unroll
    for (int m = 0; m < FM; ++m) {
        int r = wm * (FM * 16) + m * 16 + lr;
        aBase[m] = r * 96;
        d0m[m] = lk - (r % 12);
    }
    const u16* wtw = Wt + (size_t)(wn * FN) * 512 + (size_t)lane * 8;
    const int ldsWaveBase = (tid & ~63) * 8;   // uniform per wave (u16 units)

    f32x4 acc[FM][FN];
#pragma unroll
    for (int m = 0; m < FM; ++m)
#pragma unroll
        for (int n = 0; n < FN; ++n)
            acc[m][n] = (f32x4){0.f, 0.f, 0.f, 0.f};

    auto issueA = [&](int s, int bufSel) {
        int offIdx = (HFDIV == 1) ? s : (s >> 1);
        int hf     = (HFDIV == 1) ? 0 : (s & 1);
#pragma unroll
        for (int it = 0; it < 3; ++it) {
            int sv = lsrcL[offIdx * 128 + aRow[it]];
            const u16* g = (sv >= 0)
                ? (xb + (size_t)sv * CIN + hf * 96 + aGcOff[it])
                : ((const u16*)zbuf + aGcOff[it]);
            u16* d = ldsA + bufSel * BUFU + it * 512 * 8 + ldsWaveBase;
            GLOAD_LDS16(g, d);
        }
    };

    // prologue
    issueA(0, 0);
    short8 bfC[FN], bfN[FN];
#pragma unroll
    for (int n = 0; n < FN; ++n)
        bfC[n] = *(const short8*)(wtw + (size_t)n * 512);
    __syncthreads();   // implicit vmcnt(0): A(0) resident

    int bufSel = 0;
#pragma unroll 1
    for (int s = 0; s < SG; ++s) {
        if (s + 1 < SG) issueA(s + 1, bufSel ^ 1);
        const u16* abuf = ldsA + bufSel * BUFU;
#pragma unroll
        for (int ks = 0; ks < 3; ++ks) {
            int nkidx = (ks < 2) ? (3 * s + ks + 1)
                                 : ((s + 1 < SG) ? 3 * (s + 1) : 3 * s + 2);
#pragma unroll
            for (int n = 0; n < FN; ++n)
                bfN[n] = *(const short8*)(wtw + ((size_t)nkidx * NCO + n) * 512);
            short8 af[FM];
#pragma unroll
            for (int m = 0; m < FM; ++m) {
                int c = ks * 4 + d0m[m];
                if (c < 0) c += 12;
                af[m] = *(const short8*)(abuf + aBase[m] + c * 8);
            }
#pragma unroll
            for (int n = 0; n < FN; ++n)
#pragma unroll
                for (int m = 0; m < FM; ++m)
                    acc[m][n] = __builtin_amdgcn_mfma_f32_16x16x32_bf16(
                        af[m], bfC[n], acc[m][n], 0, 0, 0);
#pragma unroll
            for (int n = 0; n < FN; ++n) bfC[n] = bfN[n];
        }
        __syncthreads();
        bufSel ^= 1;
    }

    // ---- fused BN statsA: per-block partial sum/sumsq per channel ----
    float* smf = (float*)ldsA;             // overlay [WM][COUT][2]
#pragma unroll
    for (int n = 0; n < FN; ++n) {
        float s1 = 0.f, s2 = 0.f;
#pragma unroll
        for (int m = 0; m < FM; ++m)
#pragma unroll
            for (int q = 0; q < 4; ++q) {
                float v = acc[m][n][q];
                s1 += v; s2 += v * v;
            }
        s1 += __shfl_xor(s1, 16); s1 += __shfl_xor(s1, 32);
        s2 += __shfl_xor(s2, 16); s2 += __shfl_xor(s2, 32);
        if (lane < 16) {
            int col = wn * (FN * 16) + n * 16 + lr;
            smf[(wm * COUT + col) * 2 + 0] = s1;
            smf[(wm * COUT + col) * 2 + 1] = s2;
        }
    }
    __syncthreads();
    if (tid < 2 * COUT) {
        int z = tid / COUT, cc = tid % COUT;
        float v = 0.f;
#pragma unroll
        for (int w = 0; w < WM; ++w) v += smf[(w * COUT + cc) * 2 + z];
        part[(size_t)blockIdx.x * (2 * COUT) + z * COUT + cc] = v;
    }

    // ---- store h (bf16): D layout col=lane&15, row=(lane>>4)*4+q ----
#pragma unroll
    for (int m = 0; m < FM; ++m) {
#pragma unroll
        for (int q = 0; q < 4; ++q) {
            int row = row0 + wm * (FM * 16) + m * 16 + lk * 4 + q;
            if (row < NVOX) {
#pragma unroll
                for (int n = 0; n < FN; ++n) {
                    int col = wn * (FN * 16) + n * 16 + lr;
                    hout[(size_t)row * COUT + col] = f2bf(acc[m][n][q]);
                }
            }
        }
    }
}

// ---------------------------------------------------------------------------
// BN stats reduce: sum partials over NBLK blocks, emit scale/shift
// ---------------------------------------------------------------------------
template<int COUT>
__global__ __launch_bounds__(256) void bn_statsB(
    const float* __restrict__ part, const float* __restrict__ g,
    const float* __restrict__ bv, float* __restrict__ ss)
{
    const int c = blockIdx.x;
    const int t = threadIdx.x;
    float s1 = 0.f, s2 = 0.f;
    for (int b = t; b < NBLK; b += 256) {
        s1 += part[(size_t)b * 2 * COUT + c];
        s2 += part[(size_t)b * 2 * COUT + COUT + c];
    }
#pragma unroll
    for (int d = 1; d < 64; d <<= 1) {
        s1 += __shfl_xor(s1, d);
        s2 += __shfl_xor(s2, d);
    }
    __shared__ float rs[8];
    int w = t >> 6;
    if ((t & 63) == 0) { rs[w] = s1; rs[4 + w] = s2; }
    __syncthreads();
    if (t == 0) {
        s1 = rs[0] + rs[1] + rs[2] + rs[3];
        s2 = rs[4] + rs[5] + rs[6] + rs[7];
        float mu  = s1 * (1.0f / NVOX);
        float var = s2 * (1.0f / NVOX) - mu * mu;
        float sc  = g[c] * rsqrtf(var + 1e-5f);
        ss[c] = sc;
        ss[COUT + c] = bv[c] - mu * sc;
    }
}

// ---------------------------------------------------------------------------
// apply BN + ReLU in place (bf16), vec8
// ---------------------------------------------------------------------------
template<int COUT>
__global__ __launch_bounds__(256) void bn_apply_relu(
    u16* __restrict__ h, const float* __restrict__ ss)
{
    int t = blockIdx.x * 256 + threadIdx.x;   // < NVOX*COUT/8
    int c0 = (t * 8) % COUT;
    ushort8v v = *(ushort8v*)(h + (size_t)t * 8);
#pragma unroll
    for (int j = 0; j < 8; ++j) {
        float f = bf2f(v[j]);
        f = fmaxf(f * ss[c0 + j] + ss[COUT + c0 + j], 0.f);
        v[j] = f2bf(f);
    }
    *(ushort8v*)(h + (size_t)t * 8) = v;
}

// ---------------------------------------------------------------------------
// final: out = relu(scale2*h2 + shift2 + x), f32 out, vec8
// ---------------------------------------------------------------------------
__global__ __launch_bounds__(256) void final_kernel(
    const u16* __restrict__ h2, const float* __restrict__ x,
    const float* __restrict__ ss, float* __restrict__ out)
{
    int t = blockIdx.x * 256 + threadIdx.x;   // < NVOX*96/8
    int c0 = (t * 8) % 96;
    ushort8v v = *(const ushort8v*)(h2 + (size_t)t * 8);
    float4 x0 = *(const float4*)(x + (size_t)t * 8);
    float4 x1 = *(const float4*)(x + (size_t)t * 8 + 4);
    float xs[8] = {x0.x, x0.y, x0.z, x0.w, x1.x, x1.y, x1.z, x1.w};
    float o[8];
#pragma unroll
    for (int j = 0; j < 8; ++j) {
        float f = bf2f(v[j]) * ss[c0 + j] + ss[96 + c0 + j] + xs[j];
        o[j] = fmaxf(f, 0.f);
    }
    *(float4*)(out + (size_t)t * 8)     = (float4){o[0], o[1], o[2], o[3]};
    *(float4*)(out + (size_t)t * 8 + 4) = (float4){o[4], o[5], o[6], o[7]};
}

// ---------------------------------------------------------------------------
extern "C" void kernel_launch(void* const* d_in, const int* in_sizes, int n_in,
                              void* d_out, int out_size, void* d_ws, size_t ws_size,
                              hipStream_t stream)
{
    const float* x    = (const float*)d_in[0];
    const int*   idx  = (const int*)d_in[1];
    const int*   mask = (const int*)d_in[2];
    const float* W1   = (const float*)d_in[3];
    const float* g1   = (const float*)d_in[4];
    const float* b1   = (const float*)d_in[5];
    const float* W2   = (const float*)d_in[6];
    const float* g2   = (const float*)d_in[7];
    const float* b2   = (const float*)d_in[8];

    unsigned char* ws = (unsigned char*)d_ws;
    u16*  xb    = (u16*)ws;                          // 38,400,000 B
    u16*  w1t   = (u16*)(ws + 38400000);             //    995,328 B
    u16*  w2t   = (u16*)(ws + 39395328);             //    995,328 B
    u16*  h2    = (u16*)(ws + 40390656);             // 38,400,000 B
    float* part = (float*)(ws + 78790656);           //  2,400,768 B
    float* ss1  = (float*)(ws + 81191424);           //      1,536 B
    float* ss2  = (float*)(ws + 81192960);           //        768 B
    float* zbuf = (float*)(ws + 81193728);           //        256 B

    u16* h = (u16*)d_out;         // reuse d_out (76.8MB) as [N][192] bf16

    prep_kernel<<<19236, 256, 0, stream>>>(x, W1, W2, xb, w1t, w2t, zbuf);

    // conv1: COUT=192, 2m x 4n waves, K=96 per offset
    conv_mfma<192, 4, 1><<<NBLK, 512, 0, stream>>>(xb, idx, mask, w1t, zbuf, h, part);
    bn_statsB<192><<<192, 256, 0, stream>>>(part, g1, b1, ss1);
    bn_apply_relu<192><<<18750, 256, 0, stream>>>(h, ss1);

    // conv2: COUT=96, 4m x 2n waves, K=192 in two 96-phases per offset
    conv_mfma<96, 2, 2><<<NBLK, 512, 0, stream>>>(h, idx, mask, w2t, zbuf, h2, part);
    bn_statsB<96><<<96, 256, 0, stream>>>(part, g2, b2, ss2);
    final_kernel<<<9375, 256, 0, stream>>>(h2, x, ss2, (float*)d_out);
}